// Round 4
// baseline (1522.229 us; speedup 1.0000x reference)
//
#include <hip/hip_runtime.h>
#include <hip/hip_bf16.h>

#define N_USERS 50000
#define N_ITEMS 75000
#define N_NODES (N_USERS + N_ITEMS)   // 125000
#define NNZ     1250000
#define EMB     64
#define N_LAYERS 3
#define BATCH   4096
#define CONCAT  (EMB * (N_LAYERS + 1)) // 256

// 'user' may be int64 (jax x64) or int32. Detect from data: int64 node ids
// < 2^31 have zero high words at odd int32 positions. P(false positive on
// genuine int32 data) ~ (1/50000)^4 — negligible.
__device__ __forceinline__ bool user_is_i64(const void* uptr) {
    const int* u = (const int*)uptr;
    return (u[1] | u[3] | u[5] | u[7]) == 0;
}
__device__ __forceinline__ int load_user(const void* uptr, int b, bool is64) {
    return is64 ? (int)((const long long*)uptr)[b] : ((const int*)uptr)[b];
}
__device__ __forceinline__ int sample_node(const void* user, const int* pos,
                                           const int* neg, int which, int b,
                                           bool is64) {
    if (which == 0) return load_user(user, b, is64);
    return N_USERS + (which == 1 ? pos[b] : neg[b]);
}

// ---------------------------------------------------------------------------
// init: feat(fp32) <- emb
// ---------------------------------------------------------------------------
__global__ void init_kernel(const float* __restrict__ emb,
                            float* __restrict__ feat) {
    int i = blockIdx.x * blockDim.x + threadIdx.x;
    if (i < N_NODES * EMB) feat[i] = emb[i];
}

// ---------------------------------------------------------------------------
// gather0: out columns [0,64) <- raw emb rows of the sampled nodes (fp32)
// ---------------------------------------------------------------------------
__global__ void gather0_kernel(const void* __restrict__ user,
                               const int* __restrict__ pos,
                               const int* __restrict__ neg,
                               const float* __restrict__ emb,
                               float* __restrict__ out) {
    int i = blockIdx.x * blockDim.x + threadIdx.x;  // 3*BATCH*64
    if (i >= 3 * BATCH * EMB) return;
    bool is64 = user_is_i64(user);
    int which = i / (BATCH * EMB);
    int rem   = i % (BATCH * EMB);
    int b = rem >> 6, d = rem & 63;
    int node = sample_node(user, pos, neg, which, b, is64);
    out[(which * BATCH + b) * CONCAT + d] = emb[node * EMB + d];
}

// ---------------------------------------------------------------------------
// scatter: agg[row[e]] += vals[e] * feat[col[e]]   (one thread per edge-dim)
// ---------------------------------------------------------------------------
__global__ void scatter_kernel(const int* __restrict__ row,
                               const int* __restrict__ col,
                               const float* __restrict__ vals,
                               const float* __restrict__ feat,
                               float* __restrict__ agg) {
    int i = blockIdx.x * blockDim.x + threadIdx.x;   // NNZ*64 = 80M, fits int
    if (i >= NNZ * EMB) return;
    int e = i >> 6, d = i & 63;
    int r = row[e], c = col[e];
    float v = vals[e];
    atomicAdd(&agg[r * EMB + d], v * feat[c * EMB + d]);
}

// ---------------------------------------------------------------------------
// dense: per node  p1 = lrelu(agg @ W1^T + b1), p2 = lrelu((agg*feat) @ W2^T + b2)
//        feat <- p1 + p2   (UN-normalized; normalization only at gather)
// One wave per node. W^T staged in LDS as [k][d] (broadcast + bank-free).
// ---------------------------------------------------------------------------
__global__ __launch_bounds__(256) void dense_kernel(
    const float* __restrict__ agg, float* __restrict__ feat,
    const float* __restrict__ W1, const float* __restrict__ b1,
    const float* __restrict__ W2, const float* __restrict__ b2,
    int layer) {

    __shared__ float w1t[EMB * EMB];   // w1t[k*64+d] = W1[layer][d][k]
    __shared__ float w2t[EMB * EMB];
    __shared__ float bb1[EMB], bb2[EMB];

    const int tid = threadIdx.x;
    const float* W1l = W1 + layer * EMB * EMB;
    const float* W2l = W2 + layer * EMB * EMB;
    for (int j = tid; j < EMB * EMB; j += 256) {
        int d = j >> 6, k = j & 63;
        w1t[k * EMB + d] = W1l[j];
        w2t[k * EMB + d] = W2l[j];
    }
    if (tid < EMB) {
        bb1[tid] = b1[layer * EMB + tid];
        bb2[tid] = b2[layer * EMB + tid];
    }
    __syncthreads();

    const int wave = tid >> 6, lane = tid & 63;
    const int nwaves = gridDim.x * 4;

    for (int n = blockIdx.x * 4 + wave; n < N_NODES; n += nwaves) {
        float a = agg[n * EMB + lane];
        float f = feat[n * EMB + lane];
        float g = a * f;

        float acc1 = bb1[lane];
        float acc2 = bb2[lane];
        #pragma unroll
        for (int k = 0; k < EMB; ++k) {
            float ak = __shfl(a, k, 64);
            float gk = __shfl(g, k, 64);
            acc1 += ak * w1t[k * EMB + lane];
            acc2 += gk * w2t[k * EMB + lane];
        }
        float p1 = acc1 > 0.0f ? acc1 : 0.2f * acc1;
        float p2 = acc2 > 0.0f ? acc2 : 0.2f * acc2;
        feat[n * EMB + lane] = p1 + p2;
    }
}

// ---------------------------------------------------------------------------
// gatherL: out columns [(layer+1)*64, ...) <- l2_normalize(feat)[sampled nodes]
// One wave per sample (3*BATCH waves). fp32 output.
// ---------------------------------------------------------------------------
__global__ __launch_bounds__(256) void gatherL_kernel(
    const void* __restrict__ user, const int* __restrict__ pos,
    const int* __restrict__ neg, const float* __restrict__ feat,
    float* __restrict__ out, int layer) {

    int w = blockIdx.x * 4 + (threadIdx.x >> 6);    // sample id, 0..3*BATCH
    int lane = threadIdx.x & 63;
    if (w >= 3 * BATCH) return;
    bool is64 = user_is_i64(user);
    int which = w / BATCH, b = w % BATCH;
    int node = sample_node(user, pos, neg, which, b, is64);

    float f = feat[node * EMB + lane];
    float sq = f * f;
    #pragma unroll
    for (int off = 32; off; off >>= 1) sq += __shfl_xor(sq, off, 64);
    float norm = fmaxf(sqrtf(sq), 1e-12f);

    out[w * CONCAT + (layer + 1) * EMB + lane] = f / norm;
}

extern "C" void kernel_launch(void* const* d_in, const int* in_sizes, int n_in,
                              void* d_out, int out_size, void* d_ws, size_t ws_size,
                              hipStream_t stream) {
    const void* user = d_in[0];                 // int32 or int64 — detected on device
    const int* pos  = (const int*)d_in[1];
    const int* neg  = (const int*)d_in[2];
    const int* row  = (const int*)d_in[3];
    const int* col  = (const int*)d_in[4];
    const float* vals = (const float*)d_in[5];
    const float* emb  = (const float*)d_in[6];
    const float* W1   = (const float*)d_in[7];
    const float* b1   = (const float*)d_in[8];
    const float* W2   = (const float*)d_in[9];
    const float* b2   = (const float*)d_in[10];

    // workspace: feat (32 MB) + agg (32 MB) = 64 MB
    float* feat = (float*)d_ws;
    float* agg  = feat + (size_t)N_NODES * EMB;

    float* out = (float*)d_out;   // reference output dtype is float32

    init_kernel<<<(N_NODES * EMB + 255) / 256, 256, 0, stream>>>(emb, feat);
    gather0_kernel<<<(3 * BATCH * EMB + 255) / 256, 256, 0, stream>>>(
        user, pos, neg, emb, out);

    for (int l = 0; l < N_LAYERS; ++l) {
        hipMemsetAsync(agg, 0, (size_t)N_NODES * EMB * sizeof(float), stream);
        scatter_kernel<<<(NNZ * EMB) / 256, 256, 0, stream>>>(row, col, vals, feat, agg);
        dense_kernel<<<1024, 256, 0, stream>>>(agg, feat, W1, b1, W2, b2, l);
        gatherL_kernel<<<(3 * BATCH + 3) / 4, 256, 0, stream>>>(
            user, pos, neg, feat, out, l);
    }
}

// Round 5
// 736.934 us; speedup vs baseline: 2.0656x; 2.0656x over previous
//
#include <hip/hip_runtime.h>

#define N_USERS 50000
#define N_ITEMS 75000
#define N_NODES (N_USERS + N_ITEMS)   // 125000
#define NNZ     1250000
#define EMB     64
#define N_LAYERS 3
#define BATCH   4096
#define CONCAT  (EMB * (N_LAYERS + 1)) // 256
#define NBLK_SCAN ((N_NODES + 1023) / 1024)  // 123

// 'user' may be int64 (jax x64) or int32. Detect from data.
__device__ __forceinline__ bool user_is_i64(const void* uptr) {
    const int* u = (const int*)uptr;
    return (u[1] | u[3] | u[5] | u[7]) == 0;
}
__device__ __forceinline__ int load_user(const void* uptr, int b, bool is64) {
    return is64 ? (int)((const long long*)uptr)[b] : ((const int*)uptr)[b];
}
__device__ __forceinline__ int sample_node(const void* user, const int* pos,
                                           const int* neg, int which, int b,
                                           bool is64) {
    if (which == 0) return load_user(user, b, is64);
    return N_USERS + (which == 1 ? pos[b] : neg[b]);
}

// ---------------------------------------------------------------------------
__global__ void init_kernel(const float* __restrict__ emb,
                            float* __restrict__ feat) {
    int i = blockIdx.x * blockDim.x + threadIdx.x;
    if (i < N_NODES * EMB) feat[i] = emb[i];
}

__global__ void gather0_kernel(const void* __restrict__ user,
                               const int* __restrict__ pos,
                               const int* __restrict__ neg,
                               const float* __restrict__ emb,
                               float* __restrict__ out) {
    int i = blockIdx.x * blockDim.x + threadIdx.x;  // 3*BATCH*64
    if (i >= 3 * BATCH * EMB) return;
    bool is64 = user_is_i64(user);
    int which = i / (BATCH * EMB);
    int rem   = i % (BATCH * EMB);
    int b = rem >> 6, d = rem & 63;
    int node = sample_node(user, pos, neg, which, b, is64);
    out[(which * BATCH + b) * CONCAT + d] = emb[node * EMB + d];
}

// ---------------------------------------------------------------------------
// CSR build: histogram -> exclusive scan -> bin edges (row-sorted int2 payload)
// ---------------------------------------------------------------------------
__global__ void count_kernel(const int* __restrict__ row, int* __restrict__ cnt) {
    int e = blockIdx.x * 256 + threadIdx.x;
    if (e < NNZ) atomicAdd(&cnt[row[e]], 1);
}

__global__ __launch_bounds__(256) void scan_blocks_kernel(
    const int* __restrict__ cnt, int* __restrict__ off, int* __restrict__ bsum) {
    __shared__ int s[256];
    int t = threadIdx.x, b = blockIdx.x;
    int base = b * 1024 + t * 4;
    int v0 = (base + 0 < N_NODES) ? cnt[base + 0] : 0;
    int v1 = (base + 1 < N_NODES) ? cnt[base + 1] : 0;
    int v2 = (base + 2 < N_NODES) ? cnt[base + 2] : 0;
    int v3 = (base + 3 < N_NODES) ? cnt[base + 3] : 0;
    int tsum = v0 + v1 + v2 + v3;
    s[t] = tsum;
    __syncthreads();
    for (int d = 1; d < 256; d <<= 1) {   // Hillis-Steele inclusive scan
        int x = (t >= d) ? s[t - d] : 0;
        __syncthreads();
        s[t] += x;
        __syncthreads();
    }
    int excl = s[t] - tsum;
    if (base + 0 < N_NODES) off[base + 0] = excl;
    if (base + 1 < N_NODES) off[base + 1] = excl + v0;
    if (base + 2 < N_NODES) off[base + 2] = excl + v0 + v1;
    if (base + 3 < N_NODES) off[base + 3] = excl + v0 + v1 + v2;
    if (t == 255) bsum[b] = s[255];
}

__global__ void scan_tops_kernel(int* __restrict__ bsum) {
    if (blockIdx.x == 0 && threadIdx.x == 0) {
        int run = 0;
        for (int b = 0; b < NBLK_SCAN; ++b) { int x = bsum[b]; bsum[b] = run; run += x; }
    }
}

__global__ void scan_add_kernel(int* __restrict__ off, const int* __restrict__ bsum,
                                int* __restrict__ cursor) {
    int i = blockIdx.x * 256 + threadIdx.x;
    if (i < N_NODES) {
        int v = off[i] + bsum[i >> 10];
        off[i] = v;
        cursor[i] = v;
    }
    if (i == 0) off[N_NODES] = NNZ;
}

__global__ void bin_kernel(const int* __restrict__ row, const int* __restrict__ col,
                           const float* __restrict__ vals,
                           int* __restrict__ cursor, int2* __restrict__ se) {
    int e = blockIdx.x * 256 + threadIdx.x;
    if (e >= NNZ) return;
    int r = row[e];
    int p = atomicAdd(&cursor[r], 1);
    se[p] = make_int2(col[e], __float_as_int(vals[e]));
}

// ---------------------------------------------------------------------------
// SpMM gather: one wave per node; coalesced 256B feat reads; no atomics.
// ---------------------------------------------------------------------------
__global__ __launch_bounds__(256) void spmm_kernel(
    const int* __restrict__ off, const int2* __restrict__ se,
    const float* __restrict__ feat, float* __restrict__ agg) {
    int w = blockIdx.x * 4 + (threadIdx.x >> 6);
    int lane = threadIdx.x & 63;
    if (w >= N_NODES) return;
    int j = off[w], end = off[w + 1];
    float acc = 0.f;
    while (j < end) {
        int cnt = end - j;
        int2 ev[8];
        #pragma unroll
        for (int t = 0; t < 8; ++t)
            ev[t] = (t < cnt) ? se[j + t] : make_int2(0, 0);  // val bits 0 => 0.0f
        #pragma unroll
        for (int t = 0; t < 8; ++t)
            acc += __int_as_float(ev[t].y) * feat[ev[t].x * EMB + lane];
        j += 8;
    }
    agg[w * EMB + lane] = acc;
}

// ---------------------------------------------------------------------------
// dense: p1 = lrelu(agg @ W1^T + b1), p2 = lrelu((agg*feat) @ W2^T + b2)
// Lane d holds W1/W2 row d in REGISTERS (128 VGPRs); a/g rows broadcast from
// LDS via b128 reads. Per k: 0.5 DS + 2 FMA (was 4 DS + 2 FMA).
// ---------------------------------------------------------------------------
__global__ __launch_bounds__(256) void dense_kernel(
    const float* __restrict__ agg, float* __restrict__ feat,
    const float* __restrict__ W1, const float* __restrict__ b1,
    const float* __restrict__ W2, const float* __restrict__ b2,
    int layer) {

    __shared__ float w1s[EMB * 65];   // padded: w1s[d*65+k] = W1[l][d][k]
    __shared__ float w2s[EMB * 65];
    __shared__ float sa[4][EMB];
    __shared__ float sg[4][EMB];

    const int tid = threadIdx.x, wave = tid >> 6, lane = tid & 63;
    const float* W1l = W1 + layer * EMB * EMB;
    const float* W2l = W2 + layer * EMB * EMB;
    for (int j = tid; j < EMB * EMB; j += 256) {
        int d = j >> 6, k = j & 63;
        w1s[d * 65 + k] = W1l[j];
        w2s[d * 65 + k] = W2l[j];
    }
    __syncthreads();

    float w1r[EMB], w2r[EMB];
    #pragma unroll
    for (int k = 0; k < EMB; ++k) {   // bank (lane+k)%32: 2-way = free
        w1r[k] = w1s[lane * 65 + k];
        w2r[k] = w2s[lane * 65 + k];
    }
    const float bias1 = b1[layer * EMB + lane];
    const float bias2 = b2[layer * EMB + lane];

    const int nwaves = gridDim.x * 4;
    for (int n = blockIdx.x * 4 + wave; n < N_NODES; n += nwaves) {
        float a = agg[n * EMB + lane];
        float f = feat[n * EMB + lane];
        float g = a * f;
        sa[wave][lane] = a;           // same-wave LDS write->read: ordered, no barrier
        sg[wave][lane] = g;

        float acc1 = bias1, acc2 = bias2;
        #pragma unroll
        for (int kq = 0; kq < 16; ++kq) {
            float4 av = *(const float4*)&sa[wave][kq * 4];  // broadcast b128
            float4 gv = *(const float4*)&sg[wave][kq * 4];
            acc1 += av.x * w1r[4*kq+0] + av.y * w1r[4*kq+1]
                  + av.z * w1r[4*kq+2] + av.w * w1r[4*kq+3];
            acc2 += gv.x * w2r[4*kq+0] + gv.y * w2r[4*kq+1]
                  + gv.z * w2r[4*kq+2] + gv.w * w2r[4*kq+3];
        }
        float p1 = acc1 > 0.f ? acc1 : 0.2f * acc1;
        float p2 = acc2 > 0.f ? acc2 : 0.2f * acc2;
        feat[n * EMB + lane] = p1 + p2;
    }
}

// ---------------------------------------------------------------------------
__global__ __launch_bounds__(256) void gatherL_kernel(
    const void* __restrict__ user, const int* __restrict__ pos,
    const int* __restrict__ neg, const float* __restrict__ feat,
    float* __restrict__ out, int layer) {

    int w = blockIdx.x * 4 + (threadIdx.x >> 6);
    int lane = threadIdx.x & 63;
    if (w >= 3 * BATCH) return;
    bool is64 = user_is_i64(user);
    int which = w / BATCH, b = w % BATCH;
    int node = sample_node(user, pos, neg, which, b, is64);

    float f = feat[node * EMB + lane];
    float sq = f * f;
    #pragma unroll
    for (int off = 32; off; off >>= 1) sq += __shfl_xor(sq, off, 64);
    float norm = fmaxf(sqrtf(sq), 1e-12f);

    out[w * CONCAT + (layer + 1) * EMB + lane] = f / norm;
}

extern "C" void kernel_launch(void* const* d_in, const int* in_sizes, int n_in,
                              void* d_out, int out_size, void* d_ws, size_t ws_size,
                              hipStream_t stream) {
    const void* user = d_in[0];
    const int* pos  = (const int*)d_in[1];
    const int* neg  = (const int*)d_in[2];
    const int* row  = (const int*)d_in[3];
    const int* col  = (const int*)d_in[4];
    const float* vals = (const float*)d_in[5];
    const float* emb  = (const float*)d_in[6];
    const float* W1   = (const float*)d_in[7];
    const float* b1   = (const float*)d_in[8];
    const float* W2   = (const float*)d_in[9];
    const float* b2   = (const float*)d_in[10];

    // workspace: feat 32MB | agg 32MB | off/cursor/cnt/bsum ~1.5MB | se 10MB
    float* feat   = (float*)d_ws;
    float* agg    = feat + (size_t)N_NODES * EMB;
    int*   off    = (int*)(agg + (size_t)N_NODES * EMB);
    int*   cursor = off + 125008;           // off needs N_NODES+1; padded
    int*   cnt    = cursor + N_NODES;
    int*   bsum   = cnt + N_NODES;          // NBLK_SCAN=123, padded to 128
    int2*  se     = (int2*)(bsum + 128);    // 8B-aligned (offset divisible by 8)

    float* out = (float*)d_out;

    // --- CSR build (once per launch) ---
    hipMemsetAsync(cnt, 0, (size_t)N_NODES * sizeof(int), stream);
    count_kernel<<<(NNZ + 255) / 256, 256, 0, stream>>>(row, cnt);
    scan_blocks_kernel<<<NBLK_SCAN, 256, 0, stream>>>(cnt, off, bsum);
    scan_tops_kernel<<<1, 64, 0, stream>>>(bsum);
    scan_add_kernel<<<(N_NODES + 255) / 256, 256, 0, stream>>>(off, bsum, cursor);
    bin_kernel<<<(NNZ + 255) / 256, 256, 0, stream>>>(row, col, vals, cursor, se);

    init_kernel<<<(N_NODES * EMB + 255) / 256, 256, 0, stream>>>(emb, feat);
    gather0_kernel<<<(3 * BATCH * EMB + 255) / 256, 256, 0, stream>>>(
        user, pos, neg, emb, out);

    for (int l = 0; l < N_LAYERS; ++l) {
        spmm_kernel<<<(N_NODES + 3) / 4, 256, 0, stream>>>(off, se, feat, agg);
        dense_kernel<<<1024, 256, 0, stream>>>(agg, feat, W1, b1, W2, b2, l);
        gatherL_kernel<<<(3 * BATCH + 3) / 4, 256, 0, stream>>>(
            user, pos, neg, feat, out, l);
    }
}